// Round 1
// baseline (517.128 us; speedup 1.0000x reference)
//
#include <hip/hip_runtime.h>

#define NVOX 400000
#define K27 27
#define EPS_ 1e-5f

typedef __attribute__((ext_vector_type(8))) short short8;
typedef __attribute__((ext_vector_type(4))) float floatx4;
typedef __attribute__((ext_vector_type(4))) unsigned int uintx4;

// round-to-nearest-even fp32 -> bf16, packed pair (a in low 16, b in high 16)
__device__ __forceinline__ unsigned int pack2bf(float a, float b) {
    unsigned int ua = __builtin_bit_cast(unsigned int, a);
    unsigned int ub = __builtin_bit_cast(unsigned int, b);
    ua += 0x7fffu + ((ua >> 16) & 1u);
    ub += 0x7fffu + ((ub >> 16) & 1u);
    return (ua >> 16) | (ub & 0xffff0000u);
}

// W[k][ci][co] fp32 -> wt[k][co][ci] bf16 (transposed so B-fragments are
// contiguous in LDS). Also zero the 128 stats accumulators (d_ws is poisoned
// 0xAA before every launch).
__global__ void prep_weights(const float* __restrict__ w,
                             unsigned short* __restrict__ wt,
                             float* __restrict__ sums) {
    const int gid = blockIdx.x * 256 + threadIdx.x;
    if (gid < 128) sums[gid] = 0.0f;
    if (gid < K27 * 64 * 64) {
        const int k  = gid >> 12;
        const int r  = gid & 4095;
        const int co = r >> 6;
        const int ci = r & 63;
        unsigned int u =
            __builtin_bit_cast(unsigned int, w[(k << 12) + (ci << 6) + co]);
        u += 0x7fffu + ((u >> 16) & 1u);
        wt[gid] = (unsigned short)(u >> 16);
    }
}

// Tile: 64 rows x 64 out-ch per block (256 thr = 4 waves; wave w owns rows
// [w*16, w*16+16) x all 64 cols). Per k-offset: gather -> bf16 -> LDS, then
// 2 K-blocks x 4 N-tiles of mfma_f32_16x16x32_bf16 per wave.
// LDS rows padded 64->72 bf16: write phases conflict-free, reads 2-way (free).
__launch_bounds__(256)
__global__ void conv_mfma(const float* __restrict__ feat,
                          const int* __restrict__ nmap,
                          const unsigned short* __restrict__ wt,
                          float* __restrict__ out) {
    __shared__ __align__(16) unsigned short a_tile[64 * 72];
    __shared__ __align__(16) unsigned short b_tile[64 * 72];

    const int tid  = threadIdx.x;
    const int base = blockIdx.x * 64;
    const int r    = tid >> 2;   // row / co handled by this thread (0..63)
    const int part = tid & 3;    // 16-channel chunk (0..3)
    const int lane = tid & 63;
    const int wave = tid >> 6;
    const int m    = lane & 15;
    const int q    = lane >> 4;

    floatx4 acc[4];
#pragma unroll
    for (int nt = 0; nt < 4; ++nt) acc[nt] = (floatx4){0.f, 0.f, 0.f, 0.f};

    const int woff   = r * 72 + part * 16;            // LDS write offset (ushorts)
    const int a_roff = (wave * 16 + m) * 72 + q * 8;  // A-frag read base
    const int b_roff = m * 72 + q * 8;                // B-frag read base (+nt*16*72)

    for (int k = 0; k < K27; ++k) {
        const int idx = nmap[k * NVOX + base + r];
        floatx4 f0, f1, f2, f3;
        if (idx >= 0) {
            const floatx4* src = (const floatx4*)(feat + idx * 64 + part * 16);
            f0 = src[0]; f1 = src[1]; f2 = src[2]; f3 = src[3];
        } else {
            f0 = f1 = f2 = f3 = (floatx4){0.f, 0.f, 0.f, 0.f};
        }
        const uintx4* wsrc = (const uintx4*)(wt + (k * 64 + r) * 64 + part * 16);
        const uintx4 wv0 = wsrc[0];
        const uintx4 wv1 = wsrc[1];

        uintx4 av0, av1;
        av0[0] = pack2bf(f0[0], f0[1]); av0[1] = pack2bf(f0[2], f0[3]);
        av0[2] = pack2bf(f1[0], f1[1]); av0[3] = pack2bf(f1[2], f1[3]);
        av1[0] = pack2bf(f2[0], f2[1]); av1[1] = pack2bf(f2[2], f2[3]);
        av1[2] = pack2bf(f3[0], f3[1]); av1[3] = pack2bf(f3[2], f3[3]);

        __syncthreads();  // prev iteration's LDS reads complete
        *(uintx4*)(a_tile + woff)     = av0;
        *(uintx4*)(a_tile + woff + 8) = av1;
        *(uintx4*)(b_tile + woff)     = wv0;
        *(uintx4*)(b_tile + woff + 8) = wv1;
        __syncthreads();

#pragma unroll
        for (int kb = 0; kb < 2; ++kb) {
            const short8 af = *(const short8*)(a_tile + a_roff + kb * 32);
#pragma unroll
            for (int nt = 0; nt < 4; ++nt) {
                const short8 bf =
                    *(const short8*)(b_tile + b_roff + nt * (16 * 72) + kb * 32);
                acc[nt] =
                    __builtin_amdgcn_mfma_f32_16x16x32_bf16(af, bf, acc[nt], 0, 0, 0);
            }
        }
    }

    // C/D layout: col = lane&15, row = quad*4 + reg (m89-verified)
    const int row0 = base + wave * 16 + q * 4;
#pragma unroll
    for (int nt = 0; nt < 4; ++nt) {
        const int col = nt * 16 + m;
#pragma unroll
        for (int i = 0; i < 4; ++i) {
            out[(row0 + i) * 64 + col] = acc[nt][i];
        }
    }
}

// Per-channel sum and sumsq over all rows. Stride is a multiple of 16 float4s
// so each thread's 4 channels stay fixed; LDS tree keeps channel alignment.
__global__ void stats_kernel(const float* __restrict__ out,
                             float* __restrict__ sums) {
    __shared__ floatx4 s1[256];
    __shared__ floatx4 s2[256];
    const int tid = threadIdx.x;
    floatx4 sum = (floatx4){0.f, 0.f, 0.f, 0.f};
    floatx4 sq  = (floatx4){0.f, 0.f, 0.f, 0.f};
    const floatx4* p = (const floatx4*)out;
    const int total4 = NVOX * 16;
    for (int i = blockIdx.x * 256 + tid; i < total4; i += gridDim.x * 256) {
        const floatx4 v = p[i];
        sum += v;
        sq  += v * v;
    }
    s1[tid] = sum;
    s2[tid] = sq;
    __syncthreads();
    for (int off = 128; off >= 16; off >>= 1) {
        if (tid < off) {
            s1[tid] += s1[tid + off];
            s2[tid] += s2[tid + off];
        }
        __syncthreads();
    }
    if (tid < 16) {
        const floatx4 a = s1[tid];
        const floatx4 b = s2[tid];
#pragma unroll
        for (int j = 0; j < 4; ++j) {
            atomicAdd(&sums[tid * 4 + j], a[j]);
            atomicAdd(&sums[64 + tid * 4 + j], b[j]);
        }
    }
}

__global__ void bn_apply(float* __restrict__ out, const float* __restrict__ sums,
                         const float* __restrict__ gamma,
                         const float* __restrict__ beta) {
    __shared__ float sc[64];
    __shared__ float sh[64];
    const int tid = threadIdx.x;
    if (tid < 64) {
        const float inv_n = 1.0f / (float)NVOX;
        const float mean = sums[tid] * inv_n;
        const float var  = sums[64 + tid] * inv_n - mean * mean;
        const float g    = gamma[tid] * rsqrtf(var + EPS_);
        sc[tid] = g;
        sh[tid] = beta[tid] - mean * g;
    }
    __syncthreads();
    const int cg = (tid & 15) * 4;
    floatx4 scale, shift;
#pragma unroll
    for (int j = 0; j < 4; ++j) {
        scale[j] = sc[cg + j];
        shift[j] = sh[cg + j];
    }
    floatx4* p = (floatx4*)out;
    const int total4 = NVOX * 16;
    for (int i = blockIdx.x * 256 + tid; i < total4; i += gridDim.x * 256) {
        floatx4 v = p[i] * scale + shift;
#pragma unroll
        for (int j = 0; j < 4; ++j) v[j] = v[j] > 0.f ? v[j] : 0.f;
        p[i] = v;
    }
}

extern "C" void kernel_launch(void* const* d_in, const int* in_sizes, int n_in,
                              void* d_out, int out_size, void* d_ws, size_t ws_size,
                              hipStream_t stream) {
    const float* feat  = (const float*)d_in[0];
    const int*   nmap  = (const int*)d_in[1];
    const float* w     = (const float*)d_in[2];
    const float* gamma = (const float*)d_in[3];
    const float* beta  = (const float*)d_in[4];
    float* out = (float*)d_out;

    unsigned short* wt = (unsigned short*)d_ws;                       // 221184 B bf16 weights
    float* sums = (float*)((char*)d_ws + K27 * 64 * 64 * 2);          // 128 fp32 stats

    prep_weights<<<dim3(432), dim3(256), 0, stream>>>(w, wt, sums);
    conv_mfma<<<dim3(NVOX / 64), dim3(256), 0, stream>>>(feat, nmap, wt, out);
    stats_kernel<<<dim3(1024), dim3(256), 0, stream>>>(out, sums);
    bn_apply<<<dim3(1024), dim3(256), 0, stream>>>(out, sums, gamma, beta);
}